// Round 21
// baseline (453.984 us; speedup 1.0000x reference)
//
#include <hip/hip_runtime.h>
#include <hip/hip_fp16.h>
#include <cstdint>
#include <cstddef>

#define N_NODES 100000
#define N_EDGES 1600000
#define D 128
#define NLAYERS 3
#define NB 3125       // buckets of 32 nodes
#define NBLK_E 512    // edge-phase blocks (R16: scatter 47us@7%occ -> 512 blocks)
#define EPB 3125      // edges per block: 1600000/512
#define NCHUNK 8      // b-chunks of 64 for the hoff prefix decomposition
#define ENT_CAP 1024  // fill2 LDS entries; bucket max ~600 (22 sigma)

typedef float f2v __attribute__((ext_vector_type(2)));
typedef _Float16 f16x8 __attribute__((ext_vector_type(8)));
typedef float f32x4 __attribute__((ext_vector_type(4)));
typedef unsigned u32x4 __attribute__((ext_vector_type(4)));

// ---------------- CSR build: LDS-histogram counting sort ----------------
// R11: global-atomic CSR was +127us (scatter WRITE amplification 17x from
// cross-XCD line ping-pong) — bucket sort localizes CSR writes per block.
// R16 grid reshape: NBLK_E=512, b-chunked prefix kernels. Verified -14us.

__global__ __launch_bounds__(512) void hist1_kernel(const int* __restrict__ col,
                                                    int* __restrict__ hmat) {
    __shared__ int hist[NB];
    int b = blockIdx.x, t = threadIdx.x;
    for (int j = t; j < NB; j += 512) hist[j] = 0;
    __syncthreads();
    int base = b * EPB;
    for (int i = t; i < EPB; i += 512) {
        int c = col[base + i];
        atomicAdd(&hist[c >> 5], 1);  // LDS atomic
    }
    __syncthreads();
    for (int j = t; j < NB; j += 512) hmat[b * NB + j] = hist[j];
}

// bpart[c][j] = sum over b in [c*64, c*64+64) of hmat[b][j]. Coalesced.
__global__ __launch_bounds__(256) void bpart_kernel(const int* __restrict__ hmat,
                                                    int* __restrict__ bpart) {
    int j = blockIdx.x * 256 + threadIdx.x;
    int c = blockIdx.y;
    if (j < NB) {
        int s = 0;
        int b0 = c * 64;
        for (int b = b0; b < b0 + 64; b++) s += hmat[(size_t)b * NB + j];
        bpart[c * NB + j] = s;
    }
}

// Single-block exclusive scan over 3125 column totals (Σ_c bpart) -> bstart.
__global__ void bscan_kernel(const int* __restrict__ bpart, int* __restrict__ bstart,
                             int nb, int e) {
    __shared__ int lsum[1024];
    int t = threadIdx.x;
    int vals[4];
    int v0 = 0;
#pragma unroll
    for (int j = 0; j < 4; j++) {
        int idx = t * 4 + j;
        int c = 0;
        if (idx < nb) {
#pragma unroll
            for (int k = 0; k < NCHUNK; k++) c += bpart[k * NB + idx];
        }
        vals[j] = c;
        v0 += c;
    }
    lsum[t] = v0;
    __syncthreads();
    for (int off = 1; off < 1024; off <<= 1) {
        int x = (t >= off) ? lsum[t - off] : 0;
        __syncthreads();
        lsum[t] += x;
        __syncthreads();
    }
    int base = lsum[t] - v0;  // exclusive
#pragma unroll
    for (int j = 0; j < 4; j++) {
        int idx = t * 4 + j;
        if (idx < nb) {
            bstart[idx] = base;
            base += vals[j];
        }
    }
    if (t == 0) bstart[nb] = e;
}

// hoff[b][j] = raw per-column prefix (Σ_{b'<b} hmat[b'][j]); bstart added
// in scatter's cursor init. Chunk base = Σ_{c<chunk} bpart[c][j].
__global__ __launch_bounds__(256) void hoff2_kernel(const int* __restrict__ hmat,
                                                    const int* __restrict__ bpart,
                                                    int* __restrict__ hoff) {
    int j = blockIdx.x * 256 + threadIdx.x;
    int c = blockIdx.y;
    if (j < NB) {
        int run = 0;
        for (int k = 0; k < c; k++) run += bpart[k * NB + j];
        int b0 = c * 64;
        for (int b = b0; b < b0 + 64; b++) {
            hoff[(size_t)b * NB + j] = run;
            run += hmat[(size_t)b * NB + j];
        }
    }
}

// Scatter edges to exact bucket-sorted positions. LDS cursors, no global atomics.
__global__ __launch_bounds__(512) void scatter_kernel(const int* __restrict__ row,
                                                      const int* __restrict__ col,
                                                      const int* __restrict__ hoff,
                                                      const int* __restrict__ bstart,
                                                      unsigned* __restrict__ bucketbuf) {
    __shared__ int cur[NB];
    int b = blockIdx.x, t = threadIdx.x;
    for (int j = t; j < NB; j += 512)
        cur[j] = hoff[(size_t)b * NB + j] + bstart[j];
    __syncthreads();
    int base = b * EPB;
    for (int i = t; i < EPB; i += 512) {
        int r = row[base + i], c = col[base + i];
        int pos = atomicAdd(&cur[c >> 5], 1);  // LDS atomic
        bucketbuf[pos] = ((unsigned)r << 5) | (unsigned)(c & 31);
    }
}

// One block per bucket: LDS histogram of 32 local cols -> per-node offsets,
// dinv, and localized CSR scatter (contiguous ~2KB range, LDS cursors).
__global__ void fill2_kernel(const unsigned* __restrict__ bucketbuf, const int* __restrict__ bstart,
                             int* __restrict__ offsets, float* __restrict__ dinv,
                             int* __restrict__ src, int n, int e) {
    __shared__ unsigned ent[ENT_CAP];
    __shared__ int hist[32];
    __shared__ int cur[32];
    __shared__ int loff[32];
    int b = blockIdx.x, t = threadIdx.x;
    int s0 = bstart[b];
    int cnt = bstart[b + 1] - s0;
    if (cnt > ENT_CAP) cnt = ENT_CAP;
    if (t < 32) hist[t] = 0;
    __syncthreads();
    for (int i = t; i < cnt; i += 256) {
        unsigned v = bucketbuf[s0 + i];
        ent[i] = v;
        atomicAdd(&hist[v & 31], 1);
    }
    __syncthreads();
    if (t == 0) {
        int run = s0;
#pragma unroll
        for (int j = 0; j < 32; j++) {
            loff[j] = run;
            run += hist[j];
        }
    }
    __syncthreads();
    if (t < 32) {
        int node = b * 32 + t;
        int o = loff[t];
        offsets[node] = o;
        cur[t] = o;
        dinv[node] = rsqrtf((float)(hist[t] + 1));  // +1 self loop
    }
    if (b == 0 && t == 0) offsets[n] = e;
    __syncthreads();
    for (int i = t; i < cnt; i += 256) {
        unsigned v = ent[i];
        int pos = atomicAdd(&cur[v & 31], 1);
        src[pos] = (int)(v >> 5);
    }
}

// ---------------- per-layer kernels ----------------

// Cast + pre-scale: xs[v] = fp16(dinv[v] * emb[v]). Pre-scaling removes the
// per-edge dinv[src] gather + multiply from the agg inner loop.
__global__ void cast_kernel(const float2* __restrict__ in, const float* __restrict__ dinv,
                            __half2* __restrict__ out, int n2) {
    int i = blockIdx.x * 256 + threadIdx.x;
    if (i < n2) {
        float d = dinv[i >> 6];  // wave-uniform (64 half2 per node)
        float2 v = in[i];
        out[i] = __floats2half2_rn(d * v.x, d * v.y);
    }
}

// W pre-split for the hi/lo fp16 MFMA: WhT/WlT[l][col][k] (transposed,
// fragment-ready). w = wh + wl; A-side lo plane dropped in R15 (absmax
// unchanged at 9.77e-4 — xs-gather rounding dominates).
__global__ void wsplit_kernel(const float* __restrict__ W,
                              _Float16* __restrict__ Wh, _Float16* __restrict__ Wl) {
    int c = blockIdx.x, l = blockIdx.y, k = threadIdx.x;  // 128 threads
    float w = W[(size_t)l * 16384 + k * 128 + c];
    _Float16 h = (_Float16)w;
    float r = w - (float)h;
    Wh[(size_t)l * 16384 + c * 128 + k] = h;
    Wl[(size_t)l * 16384 + c * 128 + k] = (_Float16)r;
}

// UNFUSED aggregation — the R19-VERIFIED form (best measured: 452.5us total).
// 4 nodes per 256-thread block; wave w owns node blockIdx.x*4+w independently
// (no barrier). 16-deep main gather group. R20's 2-edge restructure FAILED
// correctness (absmax 0.127, bug unlocated after exhaustive coverage checks)
// and is reverted — do not re-attempt without a root cause.
//   a[v] = dinv[v] * ( xs[v] + sum_e xs[src_e] ), fp32 accum -> fp16 A.
// Regular (non-NT) stores: A intermediate stays L2/L3-resident (R12/R15).
// agg plateau evidence: 8-deep=61.5, 16-deep 1-wave=59.1, 16-deep 4-wave=60.1
// us — structure-insensitive at ~3.9 TB/s EA traffic; latency/fabric-bound.
__global__ __launch_bounds__(256) void agg_kernel(
    const __half2* __restrict__ xs, const int* __restrict__ offs,
    unsigned* __restrict__ Ah,
    const float* __restrict__ dinv, const int* __restrict__ src) {
    int v = blockIdx.x * 4 + (threadIdx.x >> 6);
    int f = threadIdx.x & 63;  // lane
    float dv = dinv[v];
    float2 a0 = __half22float2(xs[(size_t)v * 64 + f]);  // self term (already scaled)
    float ax = a0.x;
    float ay = a0.y;
    int i = offs[v], s1 = offs[v + 1];
    for (; i + 15 < s1; i += 16) {  // 16-deep main group
        int s[16];
#pragma unroll
        for (int j = 0; j < 16; j++) s[j] = src[i + j];
        float2 x[16];
#pragma unroll
        for (int j = 0; j < 16; j++) x[j] = __half22float2(xs[(size_t)s[j] * 64 + f]);
#pragma unroll
        for (int j = 0; j < 16; j++) {
            ax += x[j].x;
            ay += x[j].y;
        }
    }
    if (i + 7 < s1) {  // 8-deep
        int s[8];
#pragma unroll
        for (int j = 0; j < 8; j++) s[j] = src[i + j];
        float2 x[8];
#pragma unroll
        for (int j = 0; j < 8; j++) x[j] = __half22float2(xs[(size_t)s[j] * 64 + f]);
#pragma unroll
        for (int j = 0; j < 8; j++) {
            ax += x[j].x;
            ay += x[j].y;
        }
        i += 8;
    }
    if (i < s1) {  // masked tail group
        int last = s1 - 1;
        int s[8];
        float m[8];
#pragma unroll
        for (int j = 0; j < 8; j++) {
            int idx = i + j;
            bool in = idx < s1;
            s[j] = src[in ? idx : last];
            m[j] = in ? 1.0f : 0.0f;
        }
        float2 x[8];
#pragma unroll
        for (int j = 0; j < 8; j++) x[j] = __half22float2(xs[(size_t)s[j] * 64 + f]);
#pragma unroll
        for (int j = 0; j < 8; j++) {
            ax += m[j] * x[j].x;
            ay += m[j] * x[j].y;
        }
    }
    float rx = dv * ax, ry = dv * ay;
    __half2 h2 = __floats2half2_rn(rx, ry);
    Ah[(size_t)v * 64 + f] = __builtin_bit_cast(unsigned, h2);   // regular: L2/L3-resident
}

// out[M x 128] = relu(A[M x 128] @ W[128 x 128] + bias) via fp16 MFMA.
// BM=32, 3125 blocks; single fp16 A plane, W hi/lo (h = a.wh + a.wl).
// Regular loads on the A path (L2/L3 fill, R12 lesson).
__global__ __launch_bounds__(256, 6) void gemm_mfma_kernel(
    const _Float16* __restrict__ Ahp,
    const _Float16* __restrict__ Whp, const _Float16* __restrict__ Wlp,  // [col][k]
    const float* __restrict__ bias, float* __restrict__ out,
    __half2* __restrict__ xs_out, const float* __restrict__ dinv,
    int write_h, int write_out) {
    __shared__ _Float16 sA[32][136];  // [row][16 kg * 8 + 8 pad] = 8.7 KB
    int t = threadIdx.x;
    int f = t & 63;   // lane
    int w = t >> 6;   // wave 0..3 -> cols w*32 .. w*32+31
    int row0 = blockIdx.x * 32;

    // ---- stage A tile: 512 qwords (32 rows x 16), 2 per thread ----
    const u32x4* Aq = (const u32x4*)Ahp;
#pragma unroll
    for (int i = 0; i < 2; i++) {
        int qid = t + 256 * i;          // 0..511, bijective over (r, k2)
        int r = qid >> 4;               // 0..31
        int k2 = qid & 15;              // 16B k-group
        u32x4 v = Aq[(size_t)(row0 + r) * 16 + k2];   // regular load: L2/L3 fill
        *(u32x4*)&sA[r][k2 * 8] = v;
    }
    __syncthreads();

    // ---- MFMA: rows 0..31 (2 m-frags) x wave's 32 cols (2 col-frags) ----
    int lrow = f & 15, kg = f >> 4;
    f32x4 acc[2][2];  // [m][c]
#pragma unroll
    for (int m = 0; m < 2; m++)
#pragma unroll
        for (int c = 0; c < 2; c++) acc[m][c] = (f32x4){0.f, 0.f, 0.f, 0.f};

#pragma unroll
    for (int ks = 0; ks < 4; ks++) {
        int g = ks * 4 + kg;  // 8-element k-group index
        f16x8 a0 = *(const f16x8*)&sA[lrow][g * 8];
        f16x8 a1 = *(const f16x8*)&sA[16 + lrow][g * 8];
#pragma unroll
        for (int c = 0; c < 2; c++) {
            int col = w * 32 + c * 16 + lrow;
            f16x8 bh = *(const f16x8*)&Whp[(size_t)col * 128 + g * 8];
            f16x8 bl = *(const f16x8*)&Wlp[(size_t)col * 128 + g * 8];
            acc[0][c] = __builtin_amdgcn_mfma_f32_16x16x32_f16(a0, bh, acc[0][c], 0, 0, 0);
            acc[0][c] = __builtin_amdgcn_mfma_f32_16x16x32_f16(a0, bl, acc[0][c], 0, 0, 0);
            acc[1][c] = __builtin_amdgcn_mfma_f32_16x16x32_f16(a1, bh, acc[1][c], 0, 0, 0);
            acc[1][c] = __builtin_amdgcn_mfma_f32_16x16x32_f16(a1, bl, acc[1][c], 0, 0, 0);
        }
    }

    // ---- epilogue: bias + relu; C/D frag: col=lane&15, row=(lane>>4)*4+reg ----
    float bcol[2];
    bcol[0] = bias[w * 32 + 0 * 16 + lrow];
    bcol[1] = bias[w * 32 + 1 * 16 + lrow];
#pragma unroll
    for (int m = 0; m < 2; m++) {
        int rbase = row0 + m * 16 + kg * 4;
#pragma unroll
        for (int j = 0; j < 4; j++) {
            int rowi = rbase + j;
            float dvr = write_h ? dinv[rowi] : 0.f;
#pragma unroll
            for (int c = 0; c < 2; c++) {
                float o = fmaxf(acc[m][c][j] + bcol[c], 0.f);
                float o2 = __shfl_xor(o, 1);  // partner col (lane^1): same row, col^1
                int col = w * 32 + c * 16 + lrow;
                if (write_out)
                    __builtin_nontemporal_store(o, out + (size_t)rowi * 128 + col);
                if (write_h && !(f & 1))
                    xs_out[(size_t)rowi * 64 + (col >> 1)] =
                        __floats2half2_rn(dvr * o, dvr * o2);
            }
        }
    }
}

// ---------------- launch ----------------

extern "C" void kernel_launch(void* const* d_in, const int* in_sizes, int n_in,
                              void* d_out, int out_size, void* d_ws, size_t ws_size,
                              hipStream_t stream) {
    const int* edge = (const int*)d_in[0];   // [2, E] int32
    const float* emb = (const float*)d_in[1];
    const float* Ws = (const float*)d_in[2]; // [L, D, D]
    const float* bs = (const float*)d_in[3]; // [L, D]
    float* out = (float*)d_out;

    const int n = N_NODES, e = N_EDGES;
    const int* row = edge;       // sources
    const int* col = edge + e;   // targets

    char* p = (char*)d_ws;
    _Float16* Ah = (_Float16*)p;
    int* hmat = (int*)p;                      // aliases Ah (dead until first agg)
    int* hoff = hmat + (size_t)NBLK_E * NB;   // 6.4 MB each
    int* bpart = hoff + (size_t)NBLK_E * NB;  // 100 KB
    p += (size_t)n * D * 2;                   // 25.6 MB  (single fp16 A plane)
    __half2* xs = (__half2*)p;                // 25.6 MB (pre-scaled fp16 features)
    unsigned* bucketbuf = (unsigned*)p;       // aliases xs: dead before cast runs
    p += (size_t)n * D * 2;
    int* csr_src  = (int*)p;    p += (size_t)e * 4;           // 6.4 MB
    float* dinv   = (float*)p;  p += (size_t)n * 4;
    int* offsets  = (int*)p;    p += (size_t)(n + 1) * 4;
    int* bstart   = (int*)p;    p += (size_t)(NB + 1) * 4;
    _Float16* WhT = (_Float16*)p; p += (size_t)NLAYERS * D * D * 2;  // 98 KB
    _Float16* WlT = (_Float16*)p; p += (size_t)NLAYERS * D * D * 2;  // 98 KB

    hist1_kernel<<<NBLK_E, 512, 0, stream>>>(col, hmat);
    bpart_kernel<<<dim3(13, NCHUNK), 256, 0, stream>>>(hmat, bpart);
    bscan_kernel<<<1, 1024, 0, stream>>>(bpart, bstart, NB, e);
    hoff2_kernel<<<dim3(13, NCHUNK), 256, 0, stream>>>(hmat, bpart, hoff);
    scatter_kernel<<<NBLK_E, 512, 0, stream>>>(row, col, hoff, bstart, bucketbuf);
    fill2_kernel<<<NB, 256, 0, stream>>>(bucketbuf, bstart, offsets, dinv, csr_src, n, e);
    wsplit_kernel<<<dim3(128, NLAYERS), 128, 0, stream>>>(Ws, WhT, WlT);

    int n2 = n * 64;  // half2 count
    cast_kernel<<<(n2 + 255) / 256, 256, 0, stream>>>((const float2*)emb, dinv, xs, n2);

    for (int l = 0; l < NLAYERS; l++) {
        agg_kernel<<<n / 4, 256, 0, stream>>>(xs, offsets, (unsigned*)Ah, dinv, csr_src);
        gemm_mfma_kernel<<<n / 32, 256, 0, stream>>>(
            Ah, WhT + (size_t)l * D * D, WlT + (size_t)l * D * D,
            bs + (size_t)l * D, out, xs, dinv,
            (l < NLAYERS - 1) ? 1 : 0, (l == NLAYERS - 1) ? 1 : 0);
    }
}

// Round 22
// 449.212 us; speedup vs baseline: 1.0106x; 1.0106x over previous
//
#include <hip/hip_runtime.h>
#include <hip/hip_fp16.h>
#include <cstdint>
#include <cstddef>

#define N_NODES 100000
#define N_EDGES 1600000
#define D 128
#define NLAYERS 3
#define NB 3125       // buckets of 32 nodes
#define NBLK_E 512    // edge-phase blocks (R16: scatter 47us@7%occ -> 512 blocks)
#define EPB 3125      // edges per block: 1600000/512
#define NCHUNK 8      // b-chunks of 64 for the hoff prefix decomposition
#define ENT_CAP 1024  // fill2 LDS entries; bucket max ~600 (22 sigma)

typedef float f2v __attribute__((ext_vector_type(2)));
typedef _Float16 f16x8 __attribute__((ext_vector_type(8)));
typedef float f32x4 __attribute__((ext_vector_type(4)));
typedef unsigned u32x4 __attribute__((ext_vector_type(4)));

// ---------------- CSR build: LDS-histogram counting sort ----------------
// R11: global-atomic CSR was +127us (scatter WRITE amplification 17x from
// cross-XCD line ping-pong) — bucket sort localizes CSR writes per block.
// R16 grid reshape: NBLK_E=512, b-chunked prefix kernels. Verified -14us.

__global__ __launch_bounds__(512) void hist1_kernel(const int* __restrict__ col,
                                                    int* __restrict__ hmat) {
    __shared__ int hist[NB];
    int b = blockIdx.x, t = threadIdx.x;
    for (int j = t; j < NB; j += 512) hist[j] = 0;
    __syncthreads();
    int base = b * EPB;
    for (int i = t; i < EPB; i += 512) {
        int c = col[base + i];
        atomicAdd(&hist[c >> 5], 1);  // LDS atomic
    }
    __syncthreads();
    for (int j = t; j < NB; j += 512) hmat[b * NB + j] = hist[j];
}

// bpart[c][j] = sum over b in [c*64, c*64+64) of hmat[b][j]. Coalesced.
__global__ __launch_bounds__(256) void bpart_kernel(const int* __restrict__ hmat,
                                                    int* __restrict__ bpart) {
    int j = blockIdx.x * 256 + threadIdx.x;
    int c = blockIdx.y;
    if (j < NB) {
        int s = 0;
        int b0 = c * 64;
        for (int b = b0; b < b0 + 64; b++) s += hmat[(size_t)b * NB + j];
        bpart[c * NB + j] = s;
    }
}

// Single-block exclusive scan over 3125 column totals (Σ_c bpart) -> bstart.
__global__ void bscan_kernel(const int* __restrict__ bpart, int* __restrict__ bstart,
                             int nb, int e) {
    __shared__ int lsum[1024];
    int t = threadIdx.x;
    int vals[4];
    int v0 = 0;
#pragma unroll
    for (int j = 0; j < 4; j++) {
        int idx = t * 4 + j;
        int c = 0;
        if (idx < nb) {
#pragma unroll
            for (int k = 0; k < NCHUNK; k++) c += bpart[k * NB + idx];
        }
        vals[j] = c;
        v0 += c;
    }
    lsum[t] = v0;
    __syncthreads();
    for (int off = 1; off < 1024; off <<= 1) {
        int x = (t >= off) ? lsum[t - off] : 0;
        __syncthreads();
        lsum[t] += x;
        __syncthreads();
    }
    int base = lsum[t] - v0;  // exclusive
#pragma unroll
    for (int j = 0; j < 4; j++) {
        int idx = t * 4 + j;
        if (idx < nb) {
            bstart[idx] = base;
            base += vals[j];
        }
    }
    if (t == 0) bstart[nb] = e;
}

// hoff[b][j] = raw per-column prefix (Σ_{b'<b} hmat[b'][j]); bstart added
// in scatter's cursor init. Chunk base = Σ_{c<chunk} bpart[c][j].
__global__ __launch_bounds__(256) void hoff2_kernel(const int* __restrict__ hmat,
                                                    const int* __restrict__ bpart,
                                                    int* __restrict__ hoff) {
    int j = blockIdx.x * 256 + threadIdx.x;
    int c = blockIdx.y;
    if (j < NB) {
        int run = 0;
        for (int k = 0; k < c; k++) run += bpart[k * NB + j];
        int b0 = c * 64;
        for (int b = b0; b < b0 + 64; b++) {
            hoff[(size_t)b * NB + j] = run;
            run += hmat[(size_t)b * NB + j];
        }
    }
}

// Scatter edges to exact bucket-sorted positions. LDS cursors, no global atomics.
__global__ __launch_bounds__(512) void scatter_kernel(const int* __restrict__ row,
                                                      const int* __restrict__ col,
                                                      const int* __restrict__ hoff,
                                                      const int* __restrict__ bstart,
                                                      unsigned* __restrict__ bucketbuf) {
    __shared__ int cur[NB];
    int b = blockIdx.x, t = threadIdx.x;
    for (int j = t; j < NB; j += 512)
        cur[j] = hoff[(size_t)b * NB + j] + bstart[j];
    __syncthreads();
    int base = b * EPB;
    for (int i = t; i < EPB; i += 512) {
        int r = row[base + i], c = col[base + i];
        int pos = atomicAdd(&cur[c >> 5], 1);  // LDS atomic
        bucketbuf[pos] = ((unsigned)r << 5) | (unsigned)(c & 31);
    }
}

// One block per bucket: LDS histogram of 32 local cols -> per-node offsets,
// dinv, and localized CSR scatter (contiguous ~2KB range, LDS cursors).
__global__ void fill2_kernel(const unsigned* __restrict__ bucketbuf, const int* __restrict__ bstart,
                             int* __restrict__ offsets, float* __restrict__ dinv,
                             int* __restrict__ src, int n, int e) {
    __shared__ unsigned ent[ENT_CAP];
    __shared__ int hist[32];
    __shared__ int cur[32];
    __shared__ int loff[32];
    int b = blockIdx.x, t = threadIdx.x;
    int s0 = bstart[b];
    int cnt = bstart[b + 1] - s0;
    if (cnt > ENT_CAP) cnt = ENT_CAP;
    if (t < 32) hist[t] = 0;
    __syncthreads();
    for (int i = t; i < cnt; i += 256) {
        unsigned v = bucketbuf[s0 + i];
        ent[i] = v;
        atomicAdd(&hist[v & 31], 1);
    }
    __syncthreads();
    if (t == 0) {
        int run = s0;
#pragma unroll
        for (int j = 0; j < 32; j++) {
            loff[j] = run;
            run += hist[j];
        }
    }
    __syncthreads();
    if (t < 32) {
        int node = b * 32 + t;
        int o = loff[t];
        offsets[node] = o;
        cur[t] = o;
        dinv[node] = rsqrtf((float)(hist[t] + 1));  // +1 self loop
    }
    if (b == 0 && t == 0) offsets[n] = e;
    __syncthreads();
    for (int i = t; i < cnt; i += 256) {
        unsigned v = ent[i];
        int pos = atomicAdd(&cur[v & 31], 1);
        src[pos] = (int)(v >> 5);
    }
}

// ---------------- per-layer kernels ----------------

// Cast + pre-scale: xs[v] = fp16(dinv[v] * emb[v]). Pre-scaling removes the
// per-edge dinv[src] gather + multiply from the agg inner loop.
__global__ void cast_kernel(const float2* __restrict__ in, const float* __restrict__ dinv,
                            __half2* __restrict__ out, int n2) {
    int i = blockIdx.x * 256 + threadIdx.x;
    if (i < n2) {
        float d = dinv[i >> 6];  // wave-uniform (64 half2 per node)
        float2 v = in[i];
        out[i] = __floats2half2_rn(d * v.x, d * v.y);
    }
}

// W pre-split for the hi/lo fp16 MFMA: WhT/WlT[l][col][k] (transposed,
// fragment-ready). w = wh + wl; A-side lo plane dropped in R15 (absmax
// unchanged at 9.77e-4 — xs-gather rounding dominates).
__global__ void wsplit_kernel(const float* __restrict__ W,
                              _Float16* __restrict__ Wh, _Float16* __restrict__ Wl) {
    int c = blockIdx.x, l = blockIdx.y, k = threadIdx.x;  // 128 threads
    float w = W[(size_t)l * 16384 + k * 128 + c];
    _Float16 h = (_Float16)w;
    float r = w - (float)h;
    Wh[(size_t)l * 16384 + c * 128 + k] = h;
    Wl[(size_t)l * 16384 + c * 128 + k] = (_Float16)r;
}

// UNFUSED aggregation (R19-verified structure: 4 nodes / 256-thread block,
// wave-independent, 16-deep main group).
// R21 change: SCALARIZE the uniform values. offs[v], s1, and every src[i+j]
// are wave-uniform; readfirstlane (identity on uniform data -> bitwise same
// results) moves the src stream to the scalar pipe (s_load/K$) and gather
// addresses to SGPR-base + lane-offset form. R21 counters: VALUBusy 51% =
// ~23 VALU instr/edge, mostly per-lane 64-bit addressing for what should be
// scalar work. Accumulator also packed (f2v -> candidate v_pk_add_f32).
//   a[v] = dinv[v] * ( xs[v] + sum_e xs[src_e] ), fp32 accum -> fp16 A.
// Regular (non-NT) stores: A intermediate stays L2/L3-resident (R12/R15).
__global__ __launch_bounds__(256) void agg_kernel(
    const __half2* __restrict__ xs, const int* __restrict__ offs,
    unsigned* __restrict__ Ah,
    const float* __restrict__ dinv, const int* __restrict__ src) {
    int v = blockIdx.x * 4 + (threadIdx.x >> 6);
    int f = threadIdx.x & 63;  // lane
    float dv = dinv[v];
    f2v acc = __builtin_bit_cast(f2v, __half22float2(xs[(size_t)v * 64 + f]));  // self
    int i = __builtin_amdgcn_readfirstlane(offs[v]);
    int s1 = __builtin_amdgcn_readfirstlane(offs[v + 1]);
    for (; i + 15 < s1; i += 16) {  // 16-deep main group, scalar src indices
        int s[16];
#pragma unroll
        for (int j = 0; j < 16; j++) s[j] = __builtin_amdgcn_readfirstlane(src[i + j]);
        f2v x[16];
#pragma unroll
        for (int j = 0; j < 16; j++)
            x[j] = __builtin_bit_cast(f2v, __half22float2(xs[(size_t)s[j] * 64 + f]));
#pragma unroll
        for (int j = 0; j < 16; j++) acc += x[j];
    }
    if (i + 7 < s1) {  // 8-deep
        int s[8];
#pragma unroll
        for (int j = 0; j < 8; j++) s[j] = __builtin_amdgcn_readfirstlane(src[i + j]);
        f2v x[8];
#pragma unroll
        for (int j = 0; j < 8; j++)
            x[j] = __builtin_bit_cast(f2v, __half22float2(xs[(size_t)s[j] * 64 + f]));
#pragma unroll
        for (int j = 0; j < 8; j++) acc += x[j];
        i += 8;
    }
    if (i < s1) {  // masked tail group (mask is wave-uniform per j)
        int last = s1 - 1;
        int s[8];
        float m[8];
#pragma unroll
        for (int j = 0; j < 8; j++) {
            int idx = i + j;
            bool in = idx < s1;
            s[j] = __builtin_amdgcn_readfirstlane(src[in ? idx : last]);
            m[j] = in ? 1.0f : 0.0f;
        }
        f2v x[8];
#pragma unroll
        for (int j = 0; j < 8; j++)
            x[j] = __builtin_bit_cast(f2v, __half22float2(xs[(size_t)s[j] * 64 + f]));
#pragma unroll
        for (int j = 0; j < 8; j++) {
            acc.x += m[j] * x[j].x;
            acc.y += m[j] * x[j].y;
        }
    }
    float rx = dv * acc.x, ry = dv * acc.y;
    __half2 h2 = __floats2half2_rn(rx, ry);
    Ah[(size_t)v * 64 + f] = __builtin_bit_cast(unsigned, h2);   // regular: L2/L3-resident
}

// out[M x 128] = relu(A[M x 128] @ W[128 x 128] + bias) via fp16 MFMA.
// BM=32, 3125 blocks; single fp16 A plane, W hi/lo (h = a.wh + a.wl).
// Regular loads on the A path (L2/L3 fill, R12 lesson).
__global__ __launch_bounds__(256, 6) void gemm_mfma_kernel(
    const _Float16* __restrict__ Ahp,
    const _Float16* __restrict__ Whp, const _Float16* __restrict__ Wlp,  // [col][k]
    const float* __restrict__ bias, float* __restrict__ out,
    __half2* __restrict__ xs_out, const float* __restrict__ dinv,
    int write_h, int write_out) {
    __shared__ _Float16 sA[32][136];  // [row][16 kg * 8 + 8 pad] = 8.7 KB
    int t = threadIdx.x;
    int f = t & 63;   // lane
    int w = t >> 6;   // wave 0..3 -> cols w*32 .. w*32+31
    int row0 = blockIdx.x * 32;

    // ---- stage A tile: 512 qwords (32 rows x 16), 2 per thread ----
    const u32x4* Aq = (const u32x4*)Ahp;
#pragma unroll
    for (int i = 0; i < 2; i++) {
        int qid = t + 256 * i;          // 0..511, bijective over (r, k2)
        int r = qid >> 4;               // 0..31
        int k2 = qid & 15;              // 16B k-group
        u32x4 v = Aq[(size_t)(row0 + r) * 16 + k2];   // regular load: L2/L3 fill
        *(u32x4*)&sA[r][k2 * 8] = v;
    }
    __syncthreads();

    // ---- MFMA: rows 0..31 (2 m-frags) x wave's 32 cols (2 col-frags) ----
    int lrow = f & 15, kg = f >> 4;
    f32x4 acc[2][2];  // [m][c]
#pragma unroll
    for (int m = 0; m < 2; m++)
#pragma unroll
        for (int c = 0; c < 2; c++) acc[m][c] = (f32x4){0.f, 0.f, 0.f, 0.f};

#pragma unroll
    for (int ks = 0; ks < 4; ks++) {
        int g = ks * 4 + kg;  // 8-element k-group index
        f16x8 a0 = *(const f16x8*)&sA[lrow][g * 8];
        f16x8 a1 = *(const f16x8*)&sA[16 + lrow][g * 8];
#pragma unroll
        for (int c = 0; c < 2; c++) {
            int col = w * 32 + c * 16 + lrow;
            f16x8 bh = *(const f16x8*)&Whp[(size_t)col * 128 + g * 8];
            f16x8 bl = *(const f16x8*)&Wlp[(size_t)col * 128 + g * 8];
            acc[0][c] = __builtin_amdgcn_mfma_f32_16x16x32_f16(a0, bh, acc[0][c], 0, 0, 0);
            acc[0][c] = __builtin_amdgcn_mfma_f32_16x16x32_f16(a0, bl, acc[0][c], 0, 0, 0);
            acc[1][c] = __builtin_amdgcn_mfma_f32_16x16x32_f16(a1, bh, acc[1][c], 0, 0, 0);
            acc[1][c] = __builtin_amdgcn_mfma_f32_16x16x32_f16(a1, bl, acc[1][c], 0, 0, 0);
        }
    }

    // ---- epilogue: bias + relu; C/D frag: col=lane&15, row=(lane>>4)*4+reg ----
    float bcol[2];
    bcol[0] = bias[w * 32 + 0 * 16 + lrow];
    bcol[1] = bias[w * 32 + 1 * 16 + lrow];
#pragma unroll
    for (int m = 0; m < 2; m++) {
        int rbase = row0 + m * 16 + kg * 4;
#pragma unroll
        for (int j = 0; j < 4; j++) {
            int rowi = rbase + j;
            float dvr = write_h ? dinv[rowi] : 0.f;
#pragma unroll
            for (int c = 0; c < 2; c++) {
                float o = fmaxf(acc[m][c][j] + bcol[c], 0.f);
                float o2 = __shfl_xor(o, 1);  // partner col (lane^1): same row, col^1
                int col = w * 32 + c * 16 + lrow;
                if (write_out)
                    __builtin_nontemporal_store(o, out + (size_t)rowi * 128 + col);
                if (write_h && !(f & 1))
                    xs_out[(size_t)rowi * 64 + (col >> 1)] =
                        __floats2half2_rn(dvr * o, dvr * o2);
            }
        }
    }
}

// ---------------- launch ----------------

extern "C" void kernel_launch(void* const* d_in, const int* in_sizes, int n_in,
                              void* d_out, int out_size, void* d_ws, size_t ws_size,
                              hipStream_t stream) {
    const int* edge = (const int*)d_in[0];   // [2, E] int32
    const float* emb = (const float*)d_in[1];
    const float* Ws = (const float*)d_in[2]; // [L, D, D]
    const float* bs = (const float*)d_in[3]; // [L, D]
    float* out = (float*)d_out;

    const int n = N_NODES, e = N_EDGES;
    const int* row = edge;       // sources
    const int* col = edge + e;   // targets

    char* p = (char*)d_ws;
    _Float16* Ah = (_Float16*)p;
    int* hmat = (int*)p;                      // aliases Ah (dead until first agg)
    int* hoff = hmat + (size_t)NBLK_E * NB;   // 6.4 MB each
    int* bpart = hoff + (size_t)NBLK_E * NB;  // 100 KB
    p += (size_t)n * D * 2;                   // 25.6 MB  (single fp16 A plane)
    __half2* xs = (__half2*)p;                // 25.6 MB (pre-scaled fp16 features)
    unsigned* bucketbuf = (unsigned*)p;       // aliases xs: dead before cast runs
    p += (size_t)n * D * 2;
    int* csr_src  = (int*)p;    p += (size_t)e * 4;           // 6.4 MB
    float* dinv   = (float*)p;  p += (size_t)n * 4;
    int* offsets  = (int*)p;    p += (size_t)(n + 1) * 4;
    int* bstart   = (int*)p;    p += (size_t)(NB + 1) * 4;
    _Float16* WhT = (_Float16*)p; p += (size_t)NLAYERS * D * D * 2;  // 98 KB
    _Float16* WlT = (_Float16*)p; p += (size_t)NLAYERS * D * D * 2;  // 98 KB

    hist1_kernel<<<NBLK_E, 512, 0, stream>>>(col, hmat);
    bpart_kernel<<<dim3(13, NCHUNK), 256, 0, stream>>>(hmat, bpart);
    bscan_kernel<<<1, 1024, 0, stream>>>(bpart, bstart, NB, e);
    hoff2_kernel<<<dim3(13, NCHUNK), 256, 0, stream>>>(hmat, bpart, hoff);
    scatter_kernel<<<NBLK_E, 512, 0, stream>>>(row, col, hoff, bstart, bucketbuf);
    fill2_kernel<<<NB, 256, 0, stream>>>(bucketbuf, bstart, offsets, dinv, csr_src, n, e);
    wsplit_kernel<<<dim3(128, NLAYERS), 128, 0, stream>>>(Ws, WhT, WlT);

    int n2 = n * 64;  // half2 count
    cast_kernel<<<(n2 + 255) / 256, 256, 0, stream>>>((const float2*)emb, dinv, xs, n2);

    for (int l = 0; l < NLAYERS; l++) {
        agg_kernel<<<n / 4, 256, 0, stream>>>(xs, offsets, (unsigned*)Ah, dinv, csr_src);
        gemm_mfma_kernel<<<n / 32, 256, 0, stream>>>(
            Ah, WhT + (size_t)l * D * D, WlT + (size_t)l * D * D,
            bs + (size_t)l * D, out, xs, dinv,
            (l < NLAYERS - 1) ? 1 : 0, (l == NLAYERS - 1) ? 1 : 0);
    }
}